// Round 3
// baseline (23.833 us; speedup 1.0000x reference)
//
#include <hip/hip_runtime.h>
#include <math.h>

// Quanvolution via Pauli back-propagation (see R1 derivation):
//  alpha_q = theta_q + w0_q (RY angles add); conjugating Z_w through the two
//  CNOT layers and the w1 RY layer gives, with A..D=cos(alpha), a..d=sin(alpha):
//   z0 = K0*A  + K1*ab
//   z1 = K2*B  + K3*A*bc + K4*ac
//   z2 = K5*AC + K6*B*cd + K7*A*bd + K8*ab*C + K9*ad
//   z3 = L1*BD + L2*AC*d + L3*Bc + L4*Ab*cD + L5*Ab + L6*ab*Cd + L7*ac*D + L8*a
//  (K/L constants from cos/sin of w1 only.)
//
// Block = 16 images. Phase 1: 3136 patches over 256 threads -> feats LDS.
// Phase 2: lane=(img,sub); the 16 (wave,sub) slots tile the 196 float4
// k-chunks, so all 16 img-lanes broadcast-read the SAME W address ->
// W traffic ~= 1x per block (33 KB), accumulators = 10/thread.
#define IMGS 16

__global__ __launch_bounds__(256) void quanv16_kernel(
    const float* __restrict__ x,     // [B, 784]
    const float* __restrict__ wts,   // [2, 4]
    const float* __restrict__ W,     // [10, 784]
    const float* __restrict__ bias,  // [10]
    float* __restrict__ out,         // [B, 10]
    int B)
{
    __shared__ __align__(16) float feats[IMGS][788];   // padded: 788%8==4 spreads banks
    __shared__ float part[4][IMGS][10];
    __shared__ float logits[IMGS][10];
    __shared__ float lsev[IMGS];
    __shared__ float scs[12];                          // w0[4], cw1[4], sw1[4]

    const int tid  = threadIdx.x;
    const int img0 = blockIdx.x * IMGS;

    if (tid < 4) {
        scs[tid] = wts[tid];                 // w0_q (raw angle, fused into theta)
        float s, c;
        sincosf(wts[4 + tid], &s, &c);       // w1_q full-accuracy
        scs[4 + tid] = c;
        scs[8 + tid] = s;
    }
    __syncthreads();

    const float4 w0  = *(const float4*)&scs[0];
    const float4 cw1 = *(const float4*)&scs[4];
    const float4 sw1 = *(const float4*)&scs[8];

    const float cc  = cw1.x*cw1.y, cs = cw1.x*sw1.y, sc = sw1.x*cw1.y, ss = sw1.x*sw1.y;
    const float ccc = cc*cw1.z, ccs = cc*sw1.z, csc = cs*cw1.z, css = cs*sw1.z;
    const float scc = sc*cw1.z, ssc = ss*cw1.z, sss = ss*sw1.z;
    const float K0 = cw1.x,      K1 = -sw1.x;
    const float K2 = cc,         K3 = -cs,         K4 = ss;
    const float K5 = ccc,        K6 = -ccs,        K7 = css,  K8 = -scc, K9 = -sss;
    const float L1 = ccc*cw1.w,  L2 = -ccc*sw1.w,  L3 = ccs*sw1.w, L4 = -csc*cw1.w;
    const float L5 = -css*sw1.w, L6 = scc*sw1.w,   L7 = ssc*cw1.w, L8 = sss*sw1.w;

    // ---------- phase 1: patches ----------
    for (int p = tid; p < IMGS * 196; p += 256) {
        const int img = p / 196;
        const int pl  = p - img * 196;
        const int gimg = img0 + img;
        if (gimg < B) {
            const int pi = pl / 14, pj = pl - pi * 14;
            const float* xp = x + (size_t)gimg * 784 + pi * 56 + pj * 2;
            const float2 t0 = *(const float2*)xp;
            const float2 t1 = *(const float2*)(xp + 28);

            float a, A, b, Bv, c, C, d, D;
            __sincosf(t0.x + w0.x, &a, &A);
            __sincosf(t0.y + w0.y, &b, &Bv);
            __sincosf(t1.x + w0.z, &c, &C);
            __sincosf(t1.y + w0.w, &d, &D);

            const float ab=a*b, bc=b*c, ac=a*c, cd=c*d, bd=b*d, ad=a*d;
            const float AC=A*C, Ab=A*b, Bc=Bv*c, BD=Bv*D, cD=c*D, Cd=C*d;

            const float z0 = K0*A  + K1*ab;
            const float z1 = K2*Bv + K3*(A*bc) + K4*ac;
            const float z2 = K5*AC + K6*(Bv*cd) + K7*(A*bd) + K8*(ab*C) + K9*ad;
            const float z3 = L1*BD + L2*(AC*d) + L3*Bc + L4*(Ab*cD) + L5*Ab
                           + L6*(ab*Cd) + L7*(ac*D) + L8*a;

            *(float4*)&feats[img][pl * 4] = make_float4(z0, z1, z2, z3);
        }
    }
    __syncthreads();

    // ---------- phase 2: GEMM, broadcast-W ----------
    const int wave = tid >> 6, lane = tid & 63;
    const int img  = lane & 15, sub = lane >> 4;
    const int slot = wave * 4 + sub;           // 0..15 tiles the k-chunks

    float acc[10];
#pragma unroll
    for (int cl = 0; cl < 10; ++cl) acc[cl] = 0.f;

#pragma unroll
    for (int it = 0; it < 13; ++it) {
        const int g = it * 16 + slot;          // float4 chunk index
        if (g < 196) {
            const float4 f = *(const float4*)&feats[img][g * 4];
#pragma unroll
            for (int cl = 0; cl < 10; ++cl) {
                const float4 wv = *(const float4*)&W[cl * 784 + g * 4]; // 16-lane broadcast
                acc[cl] = fmaf(f.x, wv.x, fmaf(f.y, wv.y,
                          fmaf(f.z, wv.z, fmaf(f.w, wv.w, acc[cl]))));
            }
        }
    }
    // reduce over sub (lanes l, l+16, l+32, l+48 share img)
#pragma unroll
    for (int cl = 0; cl < 10; ++cl) {
        acc[cl] += __shfl_down(acc[cl], 32, 64);
        acc[cl] += __shfl_down(acc[cl], 16, 64);
    }
    if (lane < 16) {
#pragma unroll
        for (int cl = 0; cl < 10; ++cl) part[wave][lane][cl] = acc[cl];
    }
    __syncthreads();

    // ---------- logits + log_softmax ----------
    if (tid < IMGS * 10) {
        const int im = tid / 10, cl = tid - (tid / 10) * 10;
        logits[im][cl] = bias[cl] + part[0][im][cl] + part[1][im][cl]
                       + part[2][im][cl] + part[3][im][cl];
    }
    __syncthreads();
    if (tid < IMGS) {
        float m = -1e30f;
#pragma unroll
        for (int j = 0; j < 10; ++j) m = fmaxf(m, logits[tid][j]);
        float s = 0.f;
#pragma unroll
        for (int j = 0; j < 10; ++j) s += __expf(logits[tid][j] - m);
        lsev[tid] = m + __logf(s);
    }
    __syncthreads();
    if (tid < IMGS * 10) {
        const int im = tid / 10, cl = tid - (tid / 10) * 10;
        if (img0 + im < B)
            out[(size_t)(img0 + im) * 10 + cl] = logits[im][cl] - lsev[im];
    }
}

extern "C" void kernel_launch(void* const* d_in, const int* in_sizes, int n_in,
                              void* d_out, int out_size, void* d_ws, size_t ws_size,
                              hipStream_t stream) {
    const float* x    = (const float*)d_in[0];
    const float* wts  = (const float*)d_in[1];
    const float* W    = (const float*)d_in[2];
    const float* bias = (const float*)d_in[3];
    float* out        = (float*)d_out;

    const int B = in_sizes[0] / 784;
    const int blocks = (B + IMGS - 1) / IMGS;
    quanv16_kernel<<<blocks, 256, 0, stream>>>(x, wts, W, bias, out, B);
}

// Round 4
// 22.250 us; speedup vs baseline: 1.0712x; 1.0712x over previous
//
#include <hip/hip_runtime.h>
#include <math.h>

// Quanvolution via Pauli back-propagation (derivation in R1):
//  alpha_q = theta_q + w0_q; with A..D=cos(alpha_q), a..d=sin(alpha_q):
//   z0 = K0*A  + K1*ab
//   z1 = K2*B  + K3*A*bc + K4*ac
//   z2 = K5*AC + K6*B*cd + K7*A*bd + K8*ab*C + K9*ad
//   z3 = L1*BD + L2*AC*d + L3*Bc + L4*Ab*cD + L5*Ab + L6*ab*Cd + L7*ac*D + L8*a
//  K/L are functions of cos/sin(w1) only -> uniform -> pinned to SGPRs.
//
// Block = 4 images (2048 blocks -> 8 blocks/CU, 32 waves/CU).
// Phase 2: lane=(img 0..3, sub 0..15); slot=wave*16+sub tiles the 196 float4
// k-chunks; 4 img-lanes broadcast-read the same W address -> W L1 traffic
// ~= 1x W per block (31 KB) instead of R1's 160 KB.
#define IMGS 4

__device__ __forceinline__ float rfl(float v) {
    return __int_as_float(__builtin_amdgcn_readfirstlane(__float_as_int(v)));
}

__global__ __launch_bounds__(256, 8) void quanv_kernel(
    const float* __restrict__ x,     // [B, 784]
    const float* __restrict__ wts,   // [2, 4]
    const float* __restrict__ W,     // [10, 784]
    const float* __restrict__ bias,  // [10]
    float* __restrict__ out,         // [B, 10]
    int B)
{
    __shared__ __align__(16) float feats[IMGS][788];
    __shared__ float part[4][IMGS][10];
    __shared__ float logits[IMGS][10];
    __shared__ float lsev[IMGS];

    const int tid  = threadIdx.x;
    const int img0 = blockIdx.x * IMGS;
    constexpr float inv2pi = 0.15915494309189535f;

    // ---- uniform weight prep (scalar loads; constants pinned to SGPRs) ----
    float cw1[4], sw1[4], w0r[4];
#pragma unroll
    for (int q = 0; q < 4; ++q) {
        w0r[q] = rfl(wts[q] * inv2pi);
        float r = wts[4 + q] * inv2pi;
        r -= floorf(r);
        cw1[q] = __builtin_amdgcn_cosf(r);
        sw1[q] = __builtin_amdgcn_sinf(r);
    }
    const float cc  = cw1[0]*cw1[1], cs = cw1[0]*sw1[1];
    const float sc  = sw1[0]*cw1[1], ss = sw1[0]*sw1[1];
    const float ccc = cc*cw1[2], ccs = cc*sw1[2], csc = cs*cw1[2], css = cs*sw1[2];
    const float scc = sc*cw1[2], ssc = ss*cw1[2], sss = ss*sw1[2];
    const float K0 = rfl(cw1[0]),       K1 = rfl(-sw1[0]);
    const float K2 = rfl(cc),           K3 = rfl(-cs),          K4 = rfl(ss);
    const float K5 = rfl(ccc),          K6 = rfl(-ccs),         K7 = rfl(css);
    const float K8 = rfl(-scc),         K9 = rfl(-sss);
    const float L1 = rfl(ccc*cw1[3]),   L2 = rfl(-ccc*sw1[3]);
    const float L3 = rfl(ccs*sw1[3]),   L4 = rfl(-csc*cw1[3]);
    const float L5 = rfl(-css*sw1[3]),  L6 = rfl(scc*sw1[3]);
    const float L7 = rfl(ssc*cw1[3]),   L8 = rfl(sss*sw1[3]);

    // ---------- phase 1: 784 patches over 256 threads ----------
#pragma unroll
    for (int it = 0; it < 4; ++it) {
        const int p = tid + it * 256;
        const int img = p / 196;
        const int pl  = p - img * 196;
        if (p < IMGS * 196 && img0 + img < B) {
            const int pi = pl / 14, pj = pl - pi * 14;
            const float* xp = x + (size_t)(img0 + img) * 784 + pi * 56 + pj * 2;
            const float2 t0 = *(const float2*)xp;
            const float2 t1 = *(const float2*)(xp + 28);

            float r;
            r = fmaf(t0.x, inv2pi, w0r[0]); r -= floorf(r);
            const float a  = __builtin_amdgcn_sinf(r), A  = __builtin_amdgcn_cosf(r);
            r = fmaf(t0.y, inv2pi, w0r[1]); r -= floorf(r);
            const float b  = __builtin_amdgcn_sinf(r), Bv = __builtin_amdgcn_cosf(r);
            r = fmaf(t1.x, inv2pi, w0r[2]); r -= floorf(r);
            const float c  = __builtin_amdgcn_sinf(r), C  = __builtin_amdgcn_cosf(r);
            r = fmaf(t1.y, inv2pi, w0r[3]); r -= floorf(r);
            const float d  = __builtin_amdgcn_sinf(r), D  = __builtin_amdgcn_cosf(r);

            const float ab=a*b, bc=b*c, ac=a*c, cd=c*d, bd=b*d, ad=a*d;
            const float AC=A*C, Ab=A*b, Bc=Bv*c, BD=Bv*D, cD=c*D, Cd=C*d;

            const float z0 = fmaf(K0, A,  K1*ab);
            const float z1 = fmaf(K2, Bv, fmaf(K3, A*bc, K4*ac));
            const float z2 = fmaf(K5, AC, fmaf(K6, Bv*cd,
                             fmaf(K7, A*bd, fmaf(K8, ab*C, K9*ad))));
            const float z3 = fmaf(L1, BD, fmaf(L2, AC*d, fmaf(L3, Bc,
                             fmaf(L4, Ab*cD, fmaf(L5, Ab, fmaf(L6, ab*Cd,
                             fmaf(L7, ac*D, L8*a)))))));

            *(float4*)&feats[img][pl * 4] = make_float4(z0, z1, z2, z3);
        }
    }
    __syncthreads();

    // ---------- phase 2: GEMM with 4-way broadcast W ----------
    const int wave = tid >> 6, lane = tid & 63;
    const int img  = lane & 3, sub = lane >> 2;   // sub 0..15
    const int slot = wave * 16 + sub;             // 0..63 tiles k-chunks

    float acc[10];
#pragma unroll
    for (int cl = 0; cl < 10; ++cl) acc[cl] = 0.f;

#pragma unroll
    for (int it = 0; it < 4; ++it) {
        const int g = it * 64 + slot;             // float4 chunk index
        if (g < 196) {
            const float4 f = *(const float4*)&feats[img][g * 4];
#pragma unroll
            for (int cl = 0; cl < 10; ++cl) {
                const float4 wv = *(const float4*)&W[cl * 784 + g * 4];
                acc[cl] = fmaf(f.x, wv.x, fmaf(f.y, wv.y,
                          fmaf(f.z, wv.z, fmaf(f.w, wv.w, acc[cl]))));
            }
        }
    }
#pragma unroll
    for (int cl = 0; cl < 10; ++cl) {
        acc[cl] += __shfl_xor(acc[cl], 4, 64);
        acc[cl] += __shfl_xor(acc[cl], 8, 64);
        acc[cl] += __shfl_xor(acc[cl], 16, 64);
        acc[cl] += __shfl_xor(acc[cl], 32, 64);
    }
    if (lane < IMGS) {
#pragma unroll
        for (int cl = 0; cl < 10; ++cl) part[wave][lane][cl] = acc[cl];
    }
    __syncthreads();

    // ---------- logits + log_softmax ----------
    if (tid < IMGS * 10) {
        const int im = tid / 10, cl = tid - (tid / 10) * 10;
        logits[im][cl] = bias[cl] + part[0][im][cl] + part[1][im][cl]
                       + part[2][im][cl] + part[3][im][cl];
    }
    __syncthreads();
    if (tid < IMGS) {
        float m = -1e30f;
#pragma unroll
        for (int j = 0; j < 10; ++j) m = fmaxf(m, logits[tid][j]);
        float s = 0.f;
#pragma unroll
        for (int j = 0; j < 10; ++j) s += __expf(logits[tid][j] - m);
        lsev[tid] = m + __logf(s);
    }
    __syncthreads();
    if (tid < IMGS * 10) {
        const int im = tid / 10, cl = tid - (tid / 10) * 10;
        if (img0 + im < B)
            out[(size_t)(img0 + im) * 10 + cl] = logits[im][cl] - lsev[im];
    }
}

extern "C" void kernel_launch(void* const* d_in, const int* in_sizes, int n_in,
                              void* d_out, int out_size, void* d_ws, size_t ws_size,
                              hipStream_t stream) {
    const float* x    = (const float*)d_in[0];
    const float* wts  = (const float*)d_in[1];
    const float* W    = (const float*)d_in[2];
    const float* bias = (const float*)d_in[3];
    float* out        = (float*)d_out;

    const int B = in_sizes[0] / 784;
    const int blocks = (B + IMGS - 1) / IMGS;
    quanv_kernel<<<blocks, 256, 0, stream>>>(x, wts, W, bias, out, B);
}

// Round 5
// 19.260 us; speedup vs baseline: 1.2375x; 1.1552x over previous
//
#include <hip/hip_runtime.h>
#include <math.h>

// Quanvolution via Pauli back-propagation (derivation R1, validated R1-R3):
//  alpha_q = theta_q + w0_q; A..D = cos(alpha_q), a..d = sin(alpha_q):
//   z0 = K0*A  + K1*ab
//   z1 = K2*B  + K3*A*bc + K4*ac
//   z2 = K5*AC + K6*B*cd + K7*A*bd + K8*ab*C + K9*ad
//   z3 = L1*BD + L2*AC*d + L3*Bc + L4*Ab*cD + L5*Ab + L6*ab*Cd + L7*ac*D + L8*a
//
// R4 structure probe: one wave = one image. No LDS, no barriers, no phases.
// Patches: 3 full 64-lane iterations + 1 masked (lanes 0..3). z FMA'd
// immediately into acc[10] against coalesced float4 W loads (W is 31 KB,
// L1-resident, shared by all waves on the CU). 6-level butterfly reduce,
// redundant all-lane log_softmax, lane 0 stores 5x float2.
#define INV2PI 0.15915494309189535f

__device__ __forceinline__ float rfl(float v) {
    return __int_as_float(__builtin_amdgcn_readfirstlane(__float_as_int(v)));
}

__global__ __launch_bounds__(256) void quanv_wave_kernel(
    const float* __restrict__ x,     // [B, 784]
    const float* __restrict__ wts,   // [2, 4]
    const float* __restrict__ W,     // [10, 784]
    const float* __restrict__ bias,  // [10]
    float* __restrict__ out,         // [B, 10]
    int B)
{
    const int lane = threadIdx.x & 63;
    const int img  = blockIdx.x * 4 + (threadIdx.x >> 6);
    if (img >= B) return;                       // wave-uniform

    // ---- uniform weight prep; constants pinned to SGPRs via readfirstlane ----
    float w0r[4], cw1[4], sw1[4];
#pragma unroll
    for (int q = 0; q < 4; ++q) {
        w0r[q] = rfl(wts[q] * INV2PI);          // w0 in revolutions
        float r = wts[4 + q] * INV2PI;          // w1 in revolutions
        r -= floorf(r);
        cw1[q] = __builtin_amdgcn_cosf(r);      // v_cos_f32: input in revs
        sw1[q] = __builtin_amdgcn_sinf(r);
    }
    const float cc  = cw1[0]*cw1[1], cs = cw1[0]*sw1[1];
    const float sc  = sw1[0]*cw1[1], ss = sw1[0]*sw1[1];
    const float ccc = cc*cw1[2], ccs = cc*sw1[2], csc = cs*cw1[2], css = cs*sw1[2];
    const float scc = sc*cw1[2], ssc = ss*cw1[2], sss = ss*sw1[2];
    const float K0 = rfl(cw1[0]),       K1 = rfl(-sw1[0]);
    const float K2 = rfl(cc),           K3 = rfl(-cs),          K4 = rfl(ss);
    const float K5 = rfl(ccc),          K6 = rfl(-ccs),         K7 = rfl(css);
    const float K8 = rfl(-scc),         K9 = rfl(-sss);
    const float L1 = rfl(ccc*cw1[3]),   L2 = rfl(-ccc*sw1[3]);
    const float L3 = rfl(ccs*sw1[3]),   L4 = rfl(-csc*cw1[3]);
    const float L5 = rfl(-css*sw1[3]),  L6 = rfl(scc*sw1[3]);
    const float L7 = rfl(ssc*cw1[3]),   L8 = rfl(sss*sw1[3]);

    const float* xim = x + (size_t)img * 784;

    float acc[10];
#pragma unroll
    for (int cl = 0; cl < 10; ++cl) acc[cl] = 0.f;

    // ---- 196 patches: compute z, FMA straight into acc ----
#pragma unroll
    for (int i = 0; i < 4; ++i) {
        const int p = i * 64 + lane;
        if (p < 196) {
            const int pi = p / 14, pj = p - pi * 14;
            const float* xp = xim + pi * 56 + pj * 2;
            const float2 t0 = *(const float2*)xp;          // q0, q1
            const float2 t1 = *(const float2*)(xp + 28);   // q2, q3

            float r;
            r = fmaf(t0.x, INV2PI, w0r[0]); r -= floorf(r);
            const float a  = __builtin_amdgcn_sinf(r), A  = __builtin_amdgcn_cosf(r);
            r = fmaf(t0.y, INV2PI, w0r[1]); r -= floorf(r);
            const float b  = __builtin_amdgcn_sinf(r), Bv = __builtin_amdgcn_cosf(r);
            r = fmaf(t1.x, INV2PI, w0r[2]); r -= floorf(r);
            const float c  = __builtin_amdgcn_sinf(r), C  = __builtin_amdgcn_cosf(r);
            r = fmaf(t1.y, INV2PI, w0r[3]); r -= floorf(r);
            const float d  = __builtin_amdgcn_sinf(r), D  = __builtin_amdgcn_cosf(r);

            const float ab=a*b, bc=b*c, ac=a*c, cd=c*d, bd=b*d, ad=a*d;
            const float AC=A*C, Ab=A*b, Bc=Bv*c, BD=Bv*D, cD=c*D, Cd=C*d;

            const float z0 = fmaf(K0, A,  K1*ab);
            const float z1 = fmaf(K2, Bv, fmaf(K3, A*bc, K4*ac));
            const float z2 = fmaf(K5, AC, fmaf(K6, Bv*cd,
                             fmaf(K7, A*bd, fmaf(K8, ab*C, K9*ad))));
            const float z3 = fmaf(L1, BD, fmaf(L2, AC*d, fmaf(L3, Bc,
                             fmaf(L4, Ab*cD, fmaf(L5, Ab, fmaf(L6, ab*Cd,
                             fmaf(L7, ac*D, L8*a)))))));

            const float* wp = W + p * 4;                   // k = 4p..4p+3
#pragma unroll
            for (int cl = 0; cl < 10; ++cl) {
                const float4 wv = *(const float4*)(wp + cl * 784);  // 1KB coalesced
                acc[cl] = fmaf(z0, wv.x, fmaf(z1, wv.y,
                          fmaf(z2, wv.z, fmaf(z3, wv.w, acc[cl]))));
            }
        }
    }

    // ---- butterfly reduce: every lane ends with the full logit vector ----
#pragma unroll
    for (int cl = 0; cl < 10; ++cl) {
        acc[cl] += __shfl_xor(acc[cl], 1, 64);
        acc[cl] += __shfl_xor(acc[cl], 2, 64);
        acc[cl] += __shfl_xor(acc[cl], 4, 64);
        acc[cl] += __shfl_xor(acc[cl], 8, 64);
        acc[cl] += __shfl_xor(acc[cl], 16, 64);
        acc[cl] += __shfl_xor(acc[cl], 32, 64);
        acc[cl] += bias[cl];
    }

    // ---- log_softmax (redundant on all lanes; uniform) ----
    float m = acc[0];
#pragma unroll
    for (int cl = 1; cl < 10; ++cl) m = fmaxf(m, acc[cl]);
    float s = 0.f;
#pragma unroll
    for (int cl = 0; cl < 10; ++cl) s += __expf(acc[cl] - m);
    const float lse = m + __logf(s);

    if (lane == 0) {
        float* op = out + (size_t)img * 10;
        *(float2*)(op + 0) = make_float2(acc[0] - lse, acc[1] - lse);
        *(float2*)(op + 2) = make_float2(acc[2] - lse, acc[3] - lse);
        *(float2*)(op + 4) = make_float2(acc[4] - lse, acc[5] - lse);
        *(float2*)(op + 6) = make_float2(acc[6] - lse, acc[7] - lse);
        *(float2*)(op + 8) = make_float2(acc[8] - lse, acc[9] - lse);
    }
}

extern "C" void kernel_launch(void* const* d_in, const int* in_sizes, int n_in,
                              void* d_out, int out_size, void* d_ws, size_t ws_size,
                              hipStream_t stream) {
    const float* x    = (const float*)d_in[0];
    const float* wts  = (const float*)d_in[1];
    const float* W    = (const float*)d_in[2];
    const float* bias = (const float*)d_in[3];
    float* out        = (float*)d_out;

    const int B = in_sizes[0] / 784;
    const int blocks = (B + 3) / 4;   // 4 waves/block, 1 image/wave
    quanv_wave_kernel<<<blocks, 256, 0, stream>>>(x, wts, W, bias, out, B);
}